// Round 2
// baseline (2623.470 us; speedup 1.0000x reference)
//
#include <hip/hip_runtime.h>
#include <hip/hip_cooperative_groups.h>

namespace cg = cooperative_groups;

// LSTM: S=512, B=128, IN=256, H=512. One persistent kernel; 256 blocks =
// 8 rowgroups (16 batch rows) x 32 colgroups (16 hidden cols x 4 gate-waves).
// Weights live in registers (bf16); c in registers; h exchanged through d_out
// with sc1 (LLC write-through) stores and sc0sc1 (cache-bypass) loads, synced
// by per-block release/acquire-style slots in d_ws.

#define SQ   512
#define BB   128
#define IN_  256
#define HH   512
#define KTOT 768
#define NKK  24
#define RG   8
#define CGN  32
#define BT   16
#define HC   16

typedef float f32x4 __attribute__((ext_vector_type(4)));
typedef short s16x8 __attribute__((ext_vector_type(8)));

struct P {
  const float *x, *h0, *c0;
  const float *W[4], *bW[4], *U[4], *bU[4];   // gate order f,i,o,g
  float* out;            // [SQ][BB][HH] h_seq, then [BB][HH] h, then [BB][HH] c
  unsigned int* cnt;     // [RG][CGN] slots, 64B apart (null in gridsync mode)
  int use_gridsync;      // 1 -> no workspace; use cooperative grid.sync()
};

__device__ __forceinline__ unsigned f2b(float f) {
  unsigned u = __float_as_uint(f);
  return (u + 0x7FFFu + ((u >> 16) & 1u)) >> 16;   // RNE to bf16
}
__device__ __forceinline__ float sigm(float x) { return 1.f / (1.f + __expf(-x)); }
__device__ __forceinline__ float tanh_(float x) {
  float e = __expf(-2.f * fabsf(x));
  float t = (1.f - e) / (1.f + e);
  return copysignf(t, x);
}

__global__ void __launch_bounds__(256, 1) lstm_all(P p) {
  __shared__ unsigned short Abuf[BT][KTOT + 8];   // [x | h] bf16, +8 pad
  __shared__ float gbuf[4][BT][HC + 1];

  const int tid = threadIdx.x;
  const int bid = blockIdx.x;
  const int r   = bid & 7;        // rowgroup
  const int cgi = bid >> 3;       // colgroup 0..31
  const int rb  = r * BT;
  const int hcb = cgi * HC;

  const int w   = tid >> 6;       // wave = gate (0=f,1=i,2=o,3=g)
  const int l   = tid & 63;
  const int l16 = l & 15;
  const int lk  = l >> 4;
  const int row16 = tid >> 4;     // staging / cell row 0..15
  const int n16   = tid & 15;

  // ---- per-wave B fragments (W then U) -> registers, once, bf16 ----
  // B layout for mfma_f32_16x16x32_bf16: lane l holds B[k=8*(l>>4)+j][col=l&15]
  const int col = hcb + l16;
  s16x8 bfrag[NKK];
#pragma unroll
  for (int kk = 0; kk < NKK; ++kk) {
    int k = kk * 32 + lk * 8;
    const float* src = (kk < 8) ? (p.W[w] + (size_t)col * IN_ + k)
                                : (p.U[w] + (size_t)col * HH + (k - IN_));
    f32x4 a = *(const f32x4*)src;
    f32x4 b = *(const f32x4*)(src + 4);
    s16x8 v;
    v[0]=(short)f2b(a.x); v[1]=(short)f2b(a.y); v[2]=(short)f2b(a.z); v[3]=(short)f2b(a.w);
    v[4]=(short)f2b(b.x); v[5]=(short)f2b(b.y); v[6]=(short)f2b(b.z); v[7]=(short)f2b(b.w);
    bfrag[kk] = v;
  }
  const float bias = p.bW[w][col] + p.bU[w][col];
  float cval = p.c0[(size_t)(rb + row16) * HH + hcb + n16];

  unsigned int* slots = p.use_gridsync ? nullptr
                                       : (p.cnt + (size_t)r * CGN * 16);
  const int aoffA = l16 * (KTOT + 8);
  const unsigned short* Afl = &Abuf[0][0];

  for (int t = 0; t < SQ; ++t) {
    // A) stage x_t (cached loads; overlaps with the slot poll below)
    {
      const float* xrow = p.x + ((size_t)t * BB + rb + row16) * IN_;
#pragma unroll
      for (int pp = 0; pp < 4; ++pp) {
        int k = pp * 64 + n16 * 4;
        f32x4 v = *(const f32x4*)(xrow + k);
        uint2 u;
        u.x = f2b(v.x) | (f2b(v.y) << 16);
        u.y = f2b(v.z) | (f2b(v.w) << 16);
        *(uint2*)&Abuf[row16][k] = u;
      }
    }
    // B) wait for all 32 blocks of this rowgroup to have published h_{t-1}
    if (t > 0 && !p.use_gridsync && tid < 64) {
      unsigned tgt = (unsigned)t;
      unsigned int* sp = slots + (size_t)(l & 31) * 16;
      int guard = 0;
      for (;;) {
        unsigned v = __hip_atomic_load(sp, __ATOMIC_RELAXED, __HIP_MEMORY_SCOPE_AGENT);
        if (__all((int)(v >= tgt))) break;
        __builtin_amdgcn_s_sleep(1);
        if (++guard > (1 << 16)) break;   // safety: fail loud, never hang
      }
    }
    __syncthreads();

    // D) load h_{t-1} rows, bypassing L1/L2 (producers stored sc1 -> LLC)
    {
      const float* hrow = (t == 0)
          ? (p.h0 + (size_t)(rb + row16) * HH)
          : (p.out + ((size_t)(t - 1) * BB + rb + row16) * HH);
      const float* hbase = hrow + n16 * 4;
      f32x4 h0v,h1v,h2v,h3v,h4v,h5v,h6v,h7v;
      asm volatile(
        "global_load_dwordx4 %0, %8, off sc0 sc1\n\t"
        "global_load_dwordx4 %1, %8, off offset:256 sc0 sc1\n\t"
        "global_load_dwordx4 %2, %8, off offset:512 sc0 sc1\n\t"
        "global_load_dwordx4 %3, %8, off offset:768 sc0 sc1\n\t"
        "global_load_dwordx4 %4, %8, off offset:1024 sc0 sc1\n\t"
        "global_load_dwordx4 %5, %8, off offset:1280 sc0 sc1\n\t"
        "global_load_dwordx4 %6, %8, off offset:1536 sc0 sc1\n\t"
        "global_load_dwordx4 %7, %8, off offset:1792 sc0 sc1\n\t"
        "s_waitcnt vmcnt(0)"
        : "=&v"(h0v), "=&v"(h1v), "=&v"(h2v), "=&v"(h3v),
          "=&v"(h4v), "=&v"(h5v), "=&v"(h6v), "=&v"(h7v)
        : "v"(hbase)
        : "memory");
      f32x4 hv[8] = {h0v,h1v,h2v,h3v,h4v,h5v,h6v,h7v};
#pragma unroll
      for (int pp = 0; pp < 8; ++pp) {
        int k = pp * 64 + n16 * 4;
        uint2 u;
        u.x = f2b(hv[pp].x) | (f2b(hv[pp].y) << 16);
        u.y = f2b(hv[pp].z) | (f2b(hv[pp].w) << 16);
        *(uint2*)&Abuf[row16][IN_ + k] = u;
      }
    }
    __syncthreads();

    // F) 24 x mfma_f32_16x16x32_bf16, two accumulator chains
    f32x4 acc0 = { bias, bias, bias, bias };
    f32x4 acc1 = { 0.f, 0.f, 0.f, 0.f };
#pragma unroll
    for (int kk = 0; kk < NKK; kk += 2) {
      s16x8 af0 = *(const s16x8*)&Afl[aoffA + kk * 32 + lk * 8];
      s16x8 af1 = *(const s16x8*)&Afl[aoffA + (kk + 1) * 32 + lk * 8];
      acc0 = __builtin_amdgcn_mfma_f32_16x16x32_bf16(af0, bfrag[kk],     acc0, 0, 0, 0);
      acc1 = __builtin_amdgcn_mfma_f32_16x16x32_bf16(af1, bfrag[kk + 1], acc1, 0, 0, 0);
    }
    // D-frag: row=(l>>4)*4+rr, col=l&15
#pragma unroll
    for (int rr = 0; rr < 4; ++rr) {
      float v = acc0[rr] + acc1[rr];
      v = (w < 3) ? sigm(v) : tanh_(v);
      gbuf[w][lk * 4 + rr][l16] = v;
    }
    __syncthreads();

    // H) cell update: one (row,col) element per thread
    float f = gbuf[0][row16][n16];
    float i = gbuf[1][row16][n16];
    float o = gbuf[2][row16][n16];
    float g = gbuf[3][row16][n16];
    cval = f * cval + i * g;
    float h = o * tanh_(cval);

    size_t oidx = ((size_t)t * BB + rb + row16) * HH + hcb + n16;
    __hip_atomic_store(p.out + oidx, h, __ATOMIC_RELAXED, __HIP_MEMORY_SCOPE_AGENT);
    if (t == SQ - 1) {
      size_t base = (size_t)SQ * BB * HH;
      size_t idx2 = (size_t)(rb + row16) * HH + hcb + n16;
      p.out[base + idx2] = h;
      p.out[base + (size_t)BB * HH + idx2] = cval;
    }
    __syncthreads();   // drains each wave's vmcnt before publish

    // J) publish step completion
    if (t < SQ - 1) {
      if (p.use_gridsync) {
        cg::this_grid().sync();
      } else if (tid == 0) {
        __hip_atomic_store(slots + (size_t)cgi * 16, (unsigned)(t + 1),
                           __ATOMIC_RELEASE, __HIP_MEMORY_SCOPE_AGENT);
      }
    }
  }
}

extern "C" void kernel_launch(void* const* d_in, const int* in_sizes, int n_in,
                              void* d_out, int out_size, void* d_ws, size_t ws_size,
                              hipStream_t stream) {
  P p;
  p.x  = (const float*)d_in[0];
  p.h0 = (const float*)d_in[1];
  p.c0 = (const float*)d_in[2];
  for (int g = 0; g < 4; ++g) {
    p.W[g]  = (const float*)d_in[3 + 4 * g];
    p.bW[g] = (const float*)d_in[4 + 4 * g];
    p.U[g]  = (const float*)d_in[5 + 4 * g];
    p.bU[g] = (const float*)d_in[6 + 4 * g];
  }
  p.out = (float*)d_out;

  const size_t need = (size_t)RG * CGN * 16 * sizeof(unsigned int);  // 16 KB
  const bool ws_ok = (d_ws != nullptr) && (ws_size >= need);
  p.use_gridsync = ws_ok ? 0 : 1;
  p.cnt = ws_ok ? (unsigned int*)d_ws : nullptr;
  if (ws_ok) hipMemsetAsync(d_ws, 0, need, stream);

  void* args[] = { &p };
  hipError_t e = hipLaunchCooperativeKernel((const void*)lstm_all,
                                            dim3(RG * CGN), dim3(256),
                                            args, 0, stream);
  if (e != hipSuccess) {
    // Fallback: plain launch. 256 blocks at <=1 block/CU on 256 CUs are
    // co-resident, so the slot-based sync remains valid.
    hipLaunchKernelGGL(lstm_all, dim3(RG * CGN), dim3(256), 0, stream, p);
  }
}